// Round 12
// baseline (147.992 us; speedup 1.0000x reference)
//
#include <hip/hip_runtime.h>
#include <cmath>

#define T_TOKENS 16384
#define DIM 2048
#define HH 64
#define NG 4
#define EPG 16
#define NE 64
#define NJ 132
#define NT 9            // n-tiles of 16 (144 padded)
#define BM 16           // tokens per block
#define KTOT 64         // ksteps of 32
#define TAU 0.02f
#define KEPS 1.5e-3f

typedef __attribute__((ext_vector_type(8))) short bf16x8;
typedef __attribute__((ext_vector_type(4))) float f32x4;

// ws float-offsets
#define WF_FLOATS (64 * NT * 64 * 4)    // fragment-linear bf16 weights, 64 ksteps
#define SUM_OFF WF_FLOATS               // 128 floats: usage, rp
#define CNT_OFF (SUM_OFF + 128)
#define LIST_OFF (CNT_OFF + 4)          // int4 entries (16B aligned)

static __device__ inline unsigned bf16rne(float x) {
    unsigned u = __float_as_uint(x);
    return (u + 0x7FFFu + ((u >> 16) & 1u)) >> 16;
}
static __device__ inline unsigned pk2trunc(float a, float b) {
    return (__float_as_uint(a) >> 16) | (__float_as_uint(b) & 0xFFFF0000u);
}

template<int N> __device__ __forceinline__ void wait_vm() {
    if constexpr (N == 0)  asm volatile("s_waitcnt vmcnt(0)" ::: "memory");
    else if constexpr (N == 4)  asm volatile("s_waitcnt vmcnt(4)" ::: "memory");
    else if constexpr (N == 5)  asm volatile("s_waitcnt vmcnt(5)" ::: "memory");
    else if constexpr (N == 8)  asm volatile("s_waitcnt vmcnt(8)" ::: "memory");
    else if constexpr (N == 10) asm volatile("s_waitcnt vmcnt(10)" ::: "memory");
}

// Build fragment-linear bf16 weight buffer: [kstep 64][ntile 9][lane 64][16B]
__global__ void moe_prep(const float* __restrict__ Wg, const float* __restrict__ We,
                         const float* __restrict__ W1, float* __restrict__ ws,
                         float* __restrict__ sums, int* __restrict__ cnt) {
    int bid = blockIdx.x;                 // 576
    int kstep = bid / NT, nt = bid % NT;
    int lane = threadIdx.x;               // 64
    if (bid == 0) {
        sums[lane] = 0.f; sums[64 + lane] = 0.f;
        if (lane == 0) *cnt = 0;
    }
    int row = nt * 16 + (lane & 15);
    int k0 = kstep * 32 + (lane >> 4) * 8;
    const float* src = nullptr;
    if (row < HH)            src = W1 + (size_t)row * DIM;
    else if (row < HH + NG)  src = Wg + (size_t)(row - HH) * DIM;
    else if (row < NJ)       src = We + (size_t)(row - HH - NG) * DIM;
    unsigned r0 = 0, r1 = 0, r2 = 0, r3 = 0;
    if (src) {
        r0 = bf16rne(src[k0 + 0]) | (bf16rne(src[k0 + 1]) << 16);
        r1 = bf16rne(src[k0 + 2]) | (bf16rne(src[k0 + 3]) << 16);
        r2 = bf16rne(src[k0 + 4]) | (bf16rne(src[k0 + 5]) << 16);
        r3 = bf16rne(src[k0 + 6]) | (bf16rne(src[k0 + 7]) << 16);
    }
    ((uint4*)ws)[(size_t)(kstep * NT + nt) * 64 + lane] = make_uint4(r0, r1, r2, r3);
}

// Barrier-free reg-direct K-loop: 3-slot pipeline, explicit counted vmcnt.
// NW = n-tiles this wave owns (2 or 3); u = loads/kstep = 2 + NW.
template<int NW>
__device__ __forceinline__ void gemm_core(const float* __restrict__ xb,
                                          const bf16x8* __restrict__ wb,
                                          f32x4* acc) {
    float4 ar[3][2];
    bf16x8 br[3][3];

#define ISSUE(T, S) do { \
    ar[S][0] = *(const float4*)(xb + (T) * 32); \
    ar[S][1] = *(const float4*)(xb + (T) * 32 + 4); \
    br[S][0] = wb[(T) * 576]; \
    br[S][1] = wb[(T) * 576 + 64]; \
    if constexpr (NW == 3) br[S][2] = wb[(T) * 576 + 128]; \
} while (0)

#define COMPUTE(S) do { \
    union { unsigned u[4]; bf16x8 v; } af; \
    af.u[0] = pk2trunc(ar[S][0].x, ar[S][0].y); \
    af.u[1] = pk2trunc(ar[S][0].z, ar[S][0].w); \
    af.u[2] = pk2trunc(ar[S][1].x, ar[S][1].y); \
    af.u[3] = pk2trunc(ar[S][1].z, ar[S][1].w); \
    acc[0] = __builtin_amdgcn_mfma_f32_16x16x32_bf16(af.v, br[S][0], acc[0], 0, 0, 0); \
    acc[1] = __builtin_amdgcn_mfma_f32_16x16x32_bf16(af.v, br[S][1], acc[1], 0, 0, 0); \
    if constexpr (NW == 3) \
        acc[2] = __builtin_amdgcn_mfma_f32_16x16x32_bf16(af.v, br[S][2], acc[2], 0, 0, 0); \
} while (0)

    ISSUE(0, 0); ISSUE(1, 1); ISSUE(2, 2);
    #pragma unroll
    for (int tb = 0; tb < 60; tb += 3) {
        wait_vm<2 * (NW + 2)>(); COMPUTE(0); ISSUE(tb + 3, 0);
        wait_vm<2 * (NW + 2)>(); COMPUTE(1); ISSUE(tb + 4, 1);
        wait_vm<2 * (NW + 2)>(); COMPUTE(2); ISSUE(tb + 5, 2);
    }
    wait_vm<2 * (NW + 2)>(); COMPUTE(0); ISSUE(63, 0);
    wait_vm<2 * (NW + 2)>(); COMPUTE(1);
    wait_vm<NW + 2>();       COMPUTE(2);
    wait_vm<0>();            COMPUTE(0);
#undef ISSUE
#undef COMPUTE
}

// Fused GEMM + epilogue: 1024 blocks x 256 threads (4 waves), 16 tokens/block.
// No LDS staging, no barriers in the K-loop; waves split the 9 n-tiles {2,2,2,3}.
__global__ __launch_bounds__(256, 4) void moe_fused(
    const float* __restrict__ x, const float* __restrict__ wfrag,
    const float* __restrict__ b1, const float* __restrict__ W2,
    const float* __restrict__ b2, const int* __restrict__ minE,
    const int* __restrict__ maxE, float* __restrict__ out,
    float* __restrict__ sums, int* __restrict__ cnt, int4* __restrict__ list) {
    __shared__ float slog[BM][145];
    __shared__ float rp_s[BM * 17];
    __shared__ float sc_n1[BM], sc_n2[BM], sc_u2[BM];
    __shared__ int   sc_e1[BM], sc_e2[BM];
    __shared__ float s_usage[NE], s_rp[NE];

    const int tid = threadIdx.x;          // 0..255
    const int wave = tid >> 6, lane = tid & 63;
    const int l15 = lane & 15, lq = lane >> 4;
    const int T0 = blockIdx.x * BM;

    if (tid < NE) { s_usage[tid] = 0.f; s_rp[tid] = 0.f; }

    // per-lane A base: token T0+l15, k-subgroup lq (8 floats)
    const float* xb = x + (size_t)(T0 + l15) * DIM + lq * 8;
    // per-lane B base: wave's first tile
    const int tile0 = wave * 2;           // waves: {0,1},{2,3},{4,5},{6,7,8}
    const bf16x8* wb = (const bf16x8*)wfrag + (size_t)tile0 * 64 + lane;

    f32x4 acc[3];
    acc[0] = (f32x4){0.f,0.f,0.f,0.f};
    acc[1] = (f32x4){0.f,0.f,0.f,0.f};
    acc[2] = (f32x4){0.f,0.f,0.f,0.f};

    if (wave == 3) gemm_core<3>(xb, wb, acc);
    else           gemm_core<2>(xb, wb, acc);

    // C/D: col = l15 (n within tile), row(token) = lq*4 + r
    #pragma unroll
    for (int r = 0; r < 4; ++r) {
        slog[lq * 4 + r][tile0 * 16 + l15]       = acc[0][r];
        slog[lq * 4 + r][(tile0 + 1) * 16 + l15] = acc[1][r];
    }
    if (wave == 3)
        #pragma unroll
        for (int r = 0; r < 4; ++r)
            slog[lq * 4 + r][8 * 16 + l15] = acc[2][r];
    __syncthreads();

    // parallel epilogue: 16 groups of 16 lanes; group t handles token t
    {
        const int t = tid >> 4;
        const int q = tid & 15;
        const int tok = T0 + t;
        const float* o = slog[t];

        float4 b1v = ((const float4*)b1)[q];
        float4 w2v = ((const float4*)W2)[q];
        float part;
        {
            float h0 = o[q * 4 + 0] + b1v.x; h0 = h0 > 0.f ? h0 : 0.f;
            float h1 = o[q * 4 + 1] + b1v.y; h1 = h1 > 0.f ? h1 : 0.f;
            float h2 = o[q * 4 + 2] + b1v.z; h2 = h2 > 0.f ? h2 : 0.f;
            float h3 = o[q * 4 + 3] + b1v.w; h3 = h3 > 0.f ? h3 : 0.f;
            part = h0 * w2v.x + h1 * w2v.y + h2 * w2v.z + h3 * w2v.w;
        }
        #pragma unroll
        for (int off = 8; off; off >>= 1) part += __shfl_xor(part, off, 16);
        float z = b2[0] + part;
        float c = 1.f / (1.f + expf(-z));
        int mx = maxE[0], mn = minE[0];
        float y = c * (float)mx;
        int k = (int)y; k = k < mn ? mn : (k > mx ? mx : k);
        int kl = (int)(y - KEPS); kl = kl < mn ? mn : (kl > mx ? mx : kl);
        int kh = (int)(y + KEPS); kh = kh < mn ? mn : (kh > mx ? mx : kh);
        bool flagK = (kl != kh);
        float u2 = (k >= 2) ? 1.f : 0.f;

        float gl0 = o[HH + 0], gl1 = o[HH + 1], gl2 = o[HH + 2], gl3 = o[HH + 3];
        float gm = gl0; int gi = 0;
        if (gl1 > gm) { gm = gl1; gi = 1; }
        if (gl2 > gm) { gm = gl2; gi = 2; }
        if (gl3 > gm) { gm = gl3; gi = 3; }
        float g2 = -INFINITY;
        if (gi != 0 && gl0 > g2) g2 = gl0;
        if (gi != 1 && gl1 > g2) g2 = gl1;
        if (gi != 2 && gl2 > g2) g2 = gl2;
        if (gi != 3 && gl3 > g2) g2 = gl3;
        bool flagG = (gm - g2) < TAU;
        float gsum = expf(gl0 - gm) + expf(gl1 - gm) + expf(gl2 - gm) + expf(gl3 - gm);
        float gp = 1.f / gsum;

        float el = o[HH + NG + gi * EPG + q];
        float v1v = el; int i1 = q;
        #pragma unroll
        for (int off = 8; off; off >>= 1) {
            float ov = __shfl_xor(v1v, off, 16);
            int   oi = __shfl_xor(i1, off, 16);
            if (ov > v1v || (ov == v1v && oi < i1)) { v1v = ov; i1 = oi; }
        }
        float v2v = (q == i1) ? -INFINITY : el; int i2 = q;
        #pragma unroll
        for (int off = 8; off; off >>= 1) {
            float ov = __shfl_xor(v2v, off, 16);
            int   oi = __shfl_xor(i2, off, 16);
            if (ov > v2v || (ov == v2v && oi < i2)) { v2v = ov; i2 = oi; }
        }
        float e3v = (q == i1 || q == i2) ? -INFINITY : el;
        #pragma unroll
        for (int off = 8; off; off >>= 1)
            e3v = fmaxf(e3v, __shfl_xor(e3v, off, 16));
        bool flagE = ((v1v - v2v) < TAU) || (u2 > 0.f && (v2v - e3v) < TAU);

        float ep = expf(el - v1v);
        float es = ep;
        #pragma unroll
        for (int off = 8; off; off >>= 1) es += __shfl_xor(es, off, 16);
        float inv = 1.f / es;
        rp_s[t * 17 + q] = gp * ep * inv;

        if (q == 0) {
            float v1p = inv;
            float v2p = expf(v2v - v1v) * inv;
            float denom = v1p + v2p * u2;
            sc_n1[t] = v1p / denom; sc_n2[t] = v2p * u2 / denom; sc_u2[t] = u2;
            sc_e1[t] = gi * EPG + i1; sc_e2[t] = gi * EPG + i2;
            if (flagK || flagG || flagE) {
                int p = atomicAdd(cnt, 1);
                int fl = (flagG ? 1 : 0) | (flagE ? 2 : 0) | (flagK ? 4 : 0);
                list[p] = make_int4(tok, fl, (int)u2, 0);
            }
        }
    }
    __syncthreads();

    float* outD = out;
    float* outC = out + (size_t)T_TOKENS * NE;
    float* outR = out + (size_t)2 * T_TOKENS * NE;
    for (int idx = tid; idx < BM * NE; idx += 256) {
        int t = idx >> 6, e = idx & 63;
        int e1i = sc_e1[t], e2i = sc_e2[t];
        int gi = e1i >> 4;
        float disp = (e == e1i ? 1.f : 0.f) + (e == e2i ? sc_u2[t] : 0.f);
        float comb = (e == e1i ? sc_n1[t] : 0.f) + (e == e2i ? sc_n2[t] : 0.f);
        float rpv  = ((e >> 4) == gi) ? rp_s[t * 17 + (e & 15)] : 0.f;
        size_t ob = (size_t)(T0 + t) * NE + e;
        outD[ob] = disp; outC[ob] = comb; outR[ob] = rpv;
        atomicAdd(&s_usage[e], disp);
        atomicAdd(&s_rp[e], rpv);
    }
    __syncthreads();
    if (tid < NE) {
        atomicAdd(&sums[tid], s_usage[tid]);
        atomicAdd(&sums[NE + tid], s_rp[tid]);
    }
}

// parallel fixup: one block (4 waves) per flagged token
__global__ __launch_bounds__(256, 4) void moe_fix(
    const float* __restrict__ x, const float* __restrict__ Wg,
    const float* __restrict__ We, const float* __restrict__ W1,
    const float* __restrict__ b1, const float* __restrict__ W2,
    const float* __restrict__ b2, const int* __restrict__ minE,
    const int* __restrict__ maxE, float* __restrict__ out,
    float* __restrict__ sums, const int* __restrict__ cnt,
    const int4* __restrict__ list) {
    __shared__ float gl_s[NG];
    __shared__ float h_s[HH];
    __shared__ float el_s[EPG];
    __shared__ float rp_row[EPG];
    __shared__ int   s_gi;
    __shared__ float s_u2, s_gp;
    __shared__ int   s_e1, s_e2;
    __shared__ float s_n1, s_n2;

    const int tid = threadIdx.x;
    const int wave = tid >> 6, lane = tid & 63;
    const int n = *cnt;

    for (int i = blockIdx.x; i < n; i += gridDim.x) {
        const int4 ent = list[i];
        const int tok = ent.x, fl = ent.y;
        const float u2_in = (float)ent.z;

        const float* xrow = x + (size_t)tok * DIM;
        float xr[32];
        #pragma unroll
        for (int m = 0; m < 32; ++m) xr[m] = xrow[lane + m * 64];

        auto dotf = [&](const float* w) -> float {
            float s = 0.f;
            #pragma unroll
            for (int m = 0; m < 32; ++m) s = fmaf(xr[m], w[lane + m * 64], s);
            #pragma unroll
            for (int off = 32; off; off >>= 1) s += __shfl_xor(s, off, 64);
            return s;
        };

        {
            float g = dotf(Wg + (size_t)wave * DIM);
            if (lane == 0) gl_s[wave] = g;
        }
        if (fl & 4) {
            for (int j = wave; j < HH; j += 4) {
                float hv = dotf(W1 + (size_t)j * DIM);
                if (lane == 0) h_s[j] = hv;
            }
        }
        __syncthreads();

        if (tid == 0) {
            float gm = -INFINITY; int gi = 0;
            #pragma unroll
            for (int g = 0; g < NG; ++g)
                if (gl_s[g] > gm) { gm = gl_s[g]; gi = g; }
            float gsum = 0.f;
            #pragma unroll
            for (int g = 0; g < NG; ++g) gsum += expf(gl_s[g] - gm);
            s_gp = 1.f / gsum;
            s_gi = gi;
            float u2 = u2_in;
            if (fl & 4) {
                float z = b2[0];
                for (int j = 0; j < HH; ++j) {
                    float h = h_s[j] + b1[j];
                    z = fmaf(W2[j], h > 0.f ? h : 0.f, z);
                }
                float c = 1.f / (1.f + expf(-z));
                int mx = maxE[0], mn = minE[0];
                int k = (int)(c * (float)mx);
                k = k < mn ? mn : (k > mx ? mx : k);
                u2 = (k >= 2) ? 1.f : 0.f;
            }
            s_u2 = u2;
        }
        __syncthreads();

        const int gi = s_gi;
        for (int j = wave; j < EPG; j += 4) {
            float e = dotf(We + (size_t)(gi * EPG + j) * DIM);
            if (lane == 0) el_s[j] = e;
        }
        __syncthreads();

        if (tid == 0) {
            float e1 = -INFINITY, e2v = -INFINITY; int i1 = 0, i2 = 0;
            #pragma unroll
            for (int j = 0; j < EPG; ++j) {
                float v = el_s[j];
                if (v > e1)       { e2v = e1; i2 = i1; e1 = v; i1 = j; }
                else if (v > e2v) { e2v = v; i2 = j; }
            }
            float es = 0.f;
            #pragma unroll
            for (int j = 0; j < EPG; ++j) {
                float e = expf(el_s[j] - e1);
                rp_row[j] = e;
                es += e;
            }
            float inv = 1.f / es;
            float gp = s_gp;
            #pragma unroll
            for (int j = 0; j < EPG; ++j) rp_row[j] *= inv * gp;
            float v1 = expf(el_s[i1] - e1) * inv;
            float v2 = expf(el_s[i2] - e1) * inv;
            float u2 = s_u2;
            float denom = v1 + v2 * u2;
            s_n1 = v1 / denom; s_n2 = v2 * u2 / denom;
            s_e1 = gi * EPG + i1; s_e2 = gi * EPG + i2;
        }
        __syncthreads();

        if (tid < NE) {
            const int e = tid;
            float u2 = s_u2;
            float newD = (e == s_e1 ? 1.f : 0.f) + (e == s_e2 ? u2 : 0.f);
            float newC = (e == s_e1 ? s_n1 : 0.f) + (e == s_e2 ? s_n2 : 0.f);
            float newR = ((e >> 4) == gi) ? rp_row[e & 15] : 0.f;
            size_t ob = (size_t)tok * NE + e;
            float oldD = out[ob];
            float oldR = out[(size_t)2 * T_TOKENS * NE + ob];
            out[ob] = newD;
            out[(size_t)T_TOKENS * NE + ob] = newC;
            out[(size_t)2 * T_TOKENS * NE + ob] = newR;
            float dD = newD - oldD, dR = newR - oldR;
            if (dD != 0.f) atomicAdd(&sums[e], dD);
            if (dR != 0.f) atomicAdd(&sums[NE + e], dR);
        }
        __syncthreads();
    }
}

__global__ void moe_finalize(const float* __restrict__ sums, float* __restrict__ out) {
    int l = threadIdx.x;
    float v = sums[l] * sums[NE + l];
    #pragma unroll
    for (int off = 32; off; off >>= 1) v += __shfl_down(v, off, 64);
    if (l == 0) {
        float N = (float)T_TOKENS;
        out[(size_t)3 * T_TOKENS * NE] = v * (float)NE / (N * N);
    }
}

extern "C" void kernel_launch(void* const* d_in, const int* in_sizes, int n_in,
                              void* d_out, int out_size, void* d_ws, size_t ws_size,
                              hipStream_t stream) {
    const float* x  = (const float*)d_in[0];
    const float* Wg = (const float*)d_in[1];
    const float* We = (const float*)d_in[2];
    const float* W1 = (const float*)d_in[3];
    const float* b1 = (const float*)d_in[4];
    const float* W2 = (const float*)d_in[5];
    const float* b2 = (const float*)d_in[6];
    const int* minE = (const int*)d_in[7];
    const int* maxE = (const int*)d_in[8];
    float* out = (float*)d_out;
    float* ws  = (float*)d_ws;

    float* wfrag = ws;
    float* sums  = ws + SUM_OFF;
    int*   cnt   = (int*)(ws + CNT_OFF);
    int4*  list  = (int4*)(ws + LIST_OFF);

    moe_prep<<<64 * NT, 64, 0, stream>>>(Wg, We, W1, wfrag, sums, cnt);
    moe_fused<<<T_TOKENS / BM, 256, 0, stream>>>(x, wfrag, b1, W2, b2, minE, maxE,
                                                 out, sums, cnt, list);
    moe_fix<<<2048, 256, 0, stream>>>(x, Wg, We, W1, b1, W2, b2, minE, maxE,
                                      out, sums, cnt, list);
    moe_finalize<<<1, 64, 0, stream>>>(sums, out);
}

// Round 13
// 125.581 us; speedup vs baseline: 1.1785x; 1.1785x over previous
//
#include <hip/hip_runtime.h>
#include <cmath>

#define T_TOKENS 16384
#define DIM 2048
#define HH 64
#define NG 4
#define EPG 16
#define NE 64
#define NJ 132
#define NJP 144
#define NT 9            // n-tiles of 16
#define BM 256          // tokens per gemm block
#define KS 4            // K-split
#define KSL (DIM / KS)  // 512 per slice
#define BK 32           // k per iteration (1 kstep)
#define NITER (KSL / BK)  // 16
#define TAU 0.02f
#define KEPS 1.5e-3f

#define XBUF_B 32768    // 256 tok * 8 units * 16B
#define WBUF_B 9216     // 9 cells * 1KB

typedef __attribute__((ext_vector_type(8))) short bf16x8;
typedef __attribute__((ext_vector_type(4))) float f32x4;

// ws float-offsets
#define WF_FLOATS (64 * NT * 64 * 4)            // 147456 floats (fragment-linear bf16 w)
#define P_OFF WF_FLOATS
#define P_FLOATS ((size_t)KS * T_TOKENS * NJP)  // 9.44M floats
#define SUM_OFF (P_OFF + P_FLOATS)
#define CNT_OFF (SUM_OFF + 128)
#define LIST_OFF (CNT_OFF + 4)

static __device__ inline unsigned bf16rne(float x) {
    unsigned u = __float_as_uint(x);
    return (u + 0x7FFFu + ((u >> 16) & 1u)) >> 16;
}

#define GLOAD_LDS(gsrc, ldst) \
    __builtin_amdgcn_global_load_lds( \
        (const __attribute__((address_space(1))) void*)(gsrc), \
        (__attribute__((address_space(3))) void*)(ldst), 16, 0, 0)

// Build fragment-linear bf16 weight buffer: [kstep 64][ntile 9][lane 64][16B]
__global__ void moe_prep(const float* __restrict__ Wg, const float* __restrict__ We,
                         const float* __restrict__ W1, float* __restrict__ ws,
                         float* __restrict__ sums, int* __restrict__ cnt) {
    int bid = blockIdx.x;                 // 576
    int kstep = bid / NT, nt = bid % NT;
    int lane = threadIdx.x;               // 64
    if (bid == 0) {
        sums[lane] = 0.f; sums[64 + lane] = 0.f;
        if (lane == 0) *cnt = 0;
    }
    int row = nt * 16 + (lane & 15);
    int k0 = kstep * 32 + (lane >> 4) * 8;
    const float* src = nullptr;
    if (row < HH)            src = W1 + (size_t)row * DIM;
    else if (row < HH + NG)  src = Wg + (size_t)(row - HH) * DIM;
    else if (row < NJ)       src = We + (size_t)(row - HH - NG) * DIM;
    unsigned r0 = 0, r1 = 0, r2 = 0, r3 = 0;
    if (src) {
        r0 = bf16rne(src[k0 + 0]) | (bf16rne(src[k0 + 1]) << 16);
        r1 = bf16rne(src[k0 + 2]) | (bf16rne(src[k0 + 3]) << 16);
        r2 = bf16rne(src[k0 + 4]) | (bf16rne(src[k0 + 5]) << 16);
        r3 = bf16rne(src[k0 + 6]) | (bf16rne(src[k0 + 7]) << 16);
    }
    ((uint4*)ws)[(size_t)(kstep * NT + nt) * 64 + lane] = make_uint4(r0, r1, r2, r3);
}

// GEMM: 256 blocks (64 tokgrp x 4 kslice) x 512 threads (8 waves), 256 tokens/block.
// Wave w owns m-tiles {2w, 2w+1} x ALL 9 n-tiles: 18 MFMA per 13 ds_read_b128 per iter.
__global__ __launch_bounds__(512, 1) void moe_gemm(
    const float* __restrict__ x, const float* __restrict__ wfrag,
    float* __restrict__ part) {
    __shared__ __align__(16) char xs[2][XBUF_B];
    __shared__ __align__(16) char wsb[2][WBUF_B];

    const int bid = blockIdx.x;
    const int tg = bid & 63, ks = bid >> 6;
    const int tid = threadIdx.x;
    const int wave = tid >> 6, lane = tid & 63;
    const int l15 = lane & 15, lq = lane >> 4;
    const int T0 = tg * BM;
    const int K0 = ks * KSL;

    // x DMA role: 4 instrs/wave; instr j covers 8 tokens.
    // lane: u_all = wave*256 + j*64 + lane; tok = u_all>>3 (= wave*32 + j*8 + (lane>>3));
    // phys unit p = lane&7; global unit = p ^ (tok&7)  (pre-swizzled source).
    const int xtokb = wave * 32 + (lane >> 3);
    const int xp = lane & 7;
    // w DMA role: wave w stages cell w; wave 0 also cell 8.
    const uint4* wg = (const uint4*)wfrag;

    // compute role
    const int mt0 = wave * 2;              // m-tiles {mt0, mt0+1}
    const int t0 = mt0 * 16 + l15;         // token of A-frag 0
    const int t1 = t0 + 16;

    f32x4 acc[2][9];
    #pragma unroll
    for (int m = 0; m < 2; ++m)
        #pragma unroll
        for (int n = 0; n < 9; ++n) acc[m][n] = (f32x4){0.f, 0.f, 0.f, 0.f};

    auto stage = [&](int it) {
        char* xb = xs[it & 1];
        char* wb = wsb[it & 1];
        const int kf = K0 + it * BK;       // k float offset
        #pragma unroll
        for (int j = 0; j < 4; ++j) {
            const int tok = xtokb + j * 8;
            const float* src = x + (size_t)(T0 + tok) * DIM + kf + ((xp ^ (tok & 7)) << 2);
            GLOAD_LDS(src, xb + (wave * 256 + j * 64) * 16);
        }
        const int kstep = ks * (KSL / 32) + it;
        const uint4* wslab = wg + (size_t)kstep * (NT * 64);
        GLOAD_LDS(wslab + wave * 64 + lane, wb + wave * 1024);
        if (wave == 0) GLOAD_LDS(wslab + 8 * 64 + lane, wb + 8 * 1024);
    };

    stage(0);
    #pragma unroll 1
    for (int it = 0; it < NITER; ++it) {
        __syncthreads();                       // stage(it) landed; prev buf free
        if (it + 1 < NITER) stage(it + 1);     // lands during this compute phase
        const char* xb = xs[it & 1];
        const char* wb = wsb[it & 1];

        // A-frags: token t, logical units {lq*2, lq*2+1}, phys = u ^ (t&7)
        union { unsigned u[4]; bf16x8 v; } a0, a1;
        {
            uint4 lo = *(const uint4*)(xb + t0 * 128 + (((lq * 2) ^ (t0 & 7)) << 4));
            uint4 hi = *(const uint4*)(xb + t0 * 128 + (((lq * 2 + 1) ^ (t0 & 7)) << 4));
            a0.u[0] = (lo.x >> 16) | (lo.y & 0xFFFF0000u);
            a0.u[1] = (lo.z >> 16) | (lo.w & 0xFFFF0000u);
            a0.u[2] = (hi.x >> 16) | (hi.y & 0xFFFF0000u);
            a0.u[3] = (hi.z >> 16) | (hi.w & 0xFFFF0000u);
        }
        {
            uint4 lo = *(const uint4*)(xb + t1 * 128 + (((lq * 2) ^ (t1 & 7)) << 4));
            uint4 hi = *(const uint4*)(xb + t1 * 128 + (((lq * 2 + 1) ^ (t1 & 7)) << 4));
            a1.u[0] = (lo.x >> 16) | (lo.y & 0xFFFF0000u);
            a1.u[1] = (lo.z >> 16) | (lo.w & 0xFFFF0000u);
            a1.u[2] = (hi.x >> 16) | (hi.y & 0xFFFF0000u);
            a1.u[3] = (hi.z >> 16) | (hi.w & 0xFFFF0000u);
        }
        #pragma unroll
        for (int n = 0; n < 9; ++n) {
            bf16x8 bv = *(const bf16x8*)(wb + n * 1024 + lane * 16);
            acc[0][n] = __builtin_amdgcn_mfma_f32_16x16x32_bf16(a0.v, bv, acc[0][n], 0, 0, 0);
            acc[1][n] = __builtin_amdgcn_mfma_f32_16x16x32_bf16(a1.v, bv, acc[1][n], 0, 0, 0);
        }
    }

    // store partials: part[ks][tok][144]; C/D: col=l15, row=lq*4+r
    float* po = part + (size_t)ks * T_TOKENS * NJP;
    #pragma unroll
    for (int m = 0; m < 2; ++m) {
        const int tokb = T0 + (mt0 + m) * 16 + lq * 4;
        #pragma unroll
        for (int n = 0; n < 9; ++n)
            #pragma unroll
            for (int r = 0; r < 4; ++r)
                po[(size_t)(tokb + r) * NJP + n * 16 + l15] = acc[m][n][r];
    }
}

// Epilogue: 1024 blocks x 256 threads, 16 tokens/block (16 lanes per token).
__global__ __launch_bounds__(256, 2) void moe_epi(
    const float* __restrict__ part,
    const float* __restrict__ b1, const float* __restrict__ W2,
    const float* __restrict__ b2, const int* __restrict__ minE,
    const int* __restrict__ maxE, float* __restrict__ out,
    float* __restrict__ sums, int* __restrict__ cnt, int4* __restrict__ list) {
    __shared__ float slog[16][145];
    __shared__ float rp_s[16 * 17];
    __shared__ float sc_n1[16], sc_n2[16], sc_u2[16];
    __shared__ int   sc_e1[16], sc_e2[16];
    __shared__ float s_usage[NE], s_rp[NE];

    const int tid = threadIdx.x;
    const int T0 = blockIdx.x * 16;
    if (tid < NE) { s_usage[tid] = 0.f; s_rp[tid] = 0.f; }

    for (int idx = tid; idx < 16 * NJP; idx += 256) {
        int t = idx / NJP, j = idx % NJP;
        float v = part[(size_t)(T0 + t) * NJP + j];
        #pragma unroll
        for (int p = 1; p < KS; ++p)
            v += part[(size_t)p * T_TOKENS * NJP + (size_t)(T0 + t) * NJP + j];
        slog[t][j] = v;
    }
    __syncthreads();

    {
        const int t = tid >> 4;
        const int q = tid & 15;
        const int tok = T0 + t;
        const float* o = slog[t];

        float4 b1v = ((const float4*)b1)[q];
        float4 w2v = ((const float4*)W2)[q];
        float part_;
        {
            float h0 = o[q * 4 + 0] + b1v.x; h0 = h0 > 0.f ? h0 : 0.f;
            float h1 = o[q * 4 + 1] + b1v.y; h1 = h1 > 0.f ? h1 : 0.f;
            float h2 = o[q * 4 + 2] + b1v.z; h2 = h2 > 0.f ? h2 : 0.f;
            float h3 = o[q * 4 + 3] + b1v.w; h3 = h3 > 0.f ? h3 : 0.f;
            part_ = h0 * w2v.x + h1 * w2v.y + h2 * w2v.z + h3 * w2v.w;
        }
        #pragma unroll
        for (int off = 8; off; off >>= 1) part_ += __shfl_xor(part_, off, 16);
        float z = b2[0] + part_;
        float c = 1.f / (1.f + expf(-z));
        int mx = maxE[0], mn = minE[0];
        float y = c * (float)mx;
        int k = (int)y; k = k < mn ? mn : (k > mx ? mx : k);
        int kl = (int)(y - KEPS); kl = kl < mn ? mn : (kl > mx ? mx : kl);
        int kh = (int)(y + KEPS); kh = kh < mn ? mn : (kh > mx ? mx : kh);
        bool flagK = (kl != kh);
        float u2 = (k >= 2) ? 1.f : 0.f;

        float gl0 = o[HH + 0], gl1 = o[HH + 1], gl2 = o[HH + 2], gl3 = o[HH + 3];
        float gm = gl0; int gi = 0;
        if (gl1 > gm) { gm = gl1; gi = 1; }
        if (gl2 > gm) { gm = gl2; gi = 2; }
        if (gl3 > gm) { gm = gl3; gi = 3; }
        float g2 = -INFINITY;
        if (gi != 0 && gl0 > g2) g2 = gl0;
        if (gi != 1 && gl1 > g2) g2 = gl1;
        if (gi != 2 && gl2 > g2) g2 = gl2;
        if (gi != 3 && gl3 > g2) g2 = gl3;
        bool flagG = (gm - g2) < TAU;
        float gsum = expf(gl0 - gm) + expf(gl1 - gm) + expf(gl2 - gm) + expf(gl3 - gm);
        float gp = 1.f / gsum;

        float el = o[HH + NG + gi * EPG + q];
        float v1v = el; int i1 = q;
        #pragma unroll
        for (int off = 8; off; off >>= 1) {
            float ov = __shfl_xor(v1v, off, 16);
            int   oi = __shfl_xor(i1, off, 16);
            if (ov > v1v || (ov == v1v && oi < i1)) { v1v = ov; i1 = oi; }
        }
        float v2v = (q == i1) ? -INFINITY : el; int i2 = q;
        #pragma unroll
        for (int off = 8; off; off >>= 1) {
            float ov = __shfl_xor(v2v, off, 16);
            int   oi = __shfl_xor(i2, off, 16);
            if (ov > v2v || (ov == v2v && oi < i2)) { v2v = ov; i2 = oi; }
        }
        float e3v = (q == i1 || q == i2) ? -INFINITY : el;
        #pragma unroll
        for (int off = 8; off; off >>= 1)
            e3v = fmaxf(e3v, __shfl_xor(e3v, off, 16));
        bool flagE = ((v1v - v2v) < TAU) || (u2 > 0.f && (v2v - e3v) < TAU);

        float ep = expf(el - v1v);
        float es = ep;
        #pragma unroll
        for (int off = 8; off; off >>= 1) es += __shfl_xor(es, off, 16);
        float inv = 1.f / es;
        rp_s[t * 17 + q] = gp * ep * inv;

        if (q == 0) {
            float v1p = inv;
            float v2p = expf(v2v - v1v) * inv;
            float denom = v1p + v2p * u2;
            sc_n1[t] = v1p / denom; sc_n2[t] = v2p * u2 / denom; sc_u2[t] = u2;
            sc_e1[t] = gi * EPG + i1; sc_e2[t] = gi * EPG + i2;
            if (flagK || flagG || flagE) {
                int p = atomicAdd(cnt, 1);
                int fl = (flagG ? 1 : 0) | (flagE ? 2 : 0) | (flagK ? 4 : 0);
                list[p] = make_int4(tok, fl, (int)u2, 0);
            }
        }
    }
    __syncthreads();

    float* outD = out;
    float* outC = out + (size_t)T_TOKENS * NE;
    float* outR = out + (size_t)2 * T_TOKENS * NE;
    for (int idx = tid; idx < 16 * NE; idx += 256) {
        int t = idx >> 6, e = idx & 63;
        int e1i = sc_e1[t], e2i = sc_e2[t];
        int gi = e1i >> 4;
        float disp = (e == e1i ? 1.f : 0.f) + (e == e2i ? sc_u2[t] : 0.f);
        float comb = (e == e1i ? sc_n1[t] : 0.f) + (e == e2i ? sc_n2[t] : 0.f);
        float rpv  = ((e >> 4) == gi) ? rp_s[t * 17 + (e & 15)] : 0.f;
        size_t ob = (size_t)(T0 + t) * NE + e;
        outD[ob] = disp; outC[ob] = comb; outR[ob] = rpv;
        atomicAdd(&s_usage[e], disp);
        atomicAdd(&s_rp[e], rpv);
    }
    __syncthreads();
    if (tid < NE) {
        atomicAdd(&sums[tid], s_usage[tid]);
        atomicAdd(&sums[NE + tid], s_rp[tid]);
    }
}

// parallel fixup: one block (4 waves) per flagged token
__global__ __launch_bounds__(256, 4) void moe_fix(
    const float* __restrict__ x, const float* __restrict__ Wg,
    const float* __restrict__ We, const float* __restrict__ W1,
    const float* __restrict__ b1, const float* __restrict__ W2,
    const float* __restrict__ b2, const int* __restrict__ minE,
    const int* __restrict__ maxE, float* __restrict__ out,
    float* __restrict__ sums, const int* __restrict__ cnt,
    const int4* __restrict__ list) {
    __shared__ float gl_s[NG];
    __shared__ float h_s[HH];
    __shared__ float el_s[EPG];
    __shared__ float rp_row[EPG];
    __shared__ int   s_gi;
    __shared__ float s_u2, s_gp;
    __shared__ int   s_e1, s_e2;
    __shared__ float s_n1, s_n2;

    const int tid = threadIdx.x;
    const int wave = tid >> 6, lane = tid & 63;
    const int n = *cnt;

    for (int i = blockIdx.x; i < n; i += gridDim.x) {
        const int4 ent = list[i];
        const int tok = ent.x, fl = ent.y;
        const float u2_in = (float)ent.z;

        const float* xrow = x + (size_t)tok * DIM;
        float xr[32];
        #pragma unroll
        for (int m = 0; m < 32; ++m) xr[m] = xrow[lane + m * 64];

        auto dotf = [&](const float* w) -> float {
            float s = 0.f;
            #pragma unroll
            for (int m = 0; m < 32; ++m) s = fmaf(xr[m], w[lane + m * 64], s);
            #pragma unroll
            for (int off = 32; off; off >>= 1) s += __shfl_xor(s, off, 64);
            return s;
        };

        {
            float g = dotf(Wg + (size_t)wave * DIM);
            if (lane == 0) gl_s[wave] = g;
        }
        if (fl & 4) {
            for (int j = wave; j < HH; j += 4) {
                float hv = dotf(W1 + (size_t)j * DIM);
                if (lane == 0) h_s[j] = hv;
            }
        }
        __syncthreads();

        if (tid == 0) {
            float gm = -INFINITY; int gi = 0;
            #pragma unroll
            for (int g = 0; g < NG; ++g)
                if (gl_s[g] > gm) { gm = gl_s[g]; gi = g; }
            float gsum = 0.f;
            #pragma unroll
            for (int g = 0; g < NG; ++g) gsum += expf(gl_s[g] - gm);
            s_gp = 1.f / gsum;
            s_gi = gi;
            float u2 = u2_in;
            if (fl & 4) {
                float z = b2[0];
                for (int j = 0; j < HH; ++j) {
                    float h = h_s[j] + b1[j];
                    z = fmaf(W2[j], h > 0.f ? h : 0.f, z);
                }
                float c = 1.f / (1.f + expf(-z));
                int mx = maxE[0], mn = minE[0];
                int k = (int)(c * (float)mx);
                k = k < mn ? mn : (k > mx ? mx : k);
                u2 = (k >= 2) ? 1.f : 0.f;
            }
            s_u2 = u2;
        }
        __syncthreads();

        const int gi = s_gi;
        for (int j = wave; j < EPG; j += 4) {
            float e = dotf(We + (size_t)(gi * EPG + j) * DIM);
            if (lane == 0) el_s[j] = e;
        }
        __syncthreads();

        if (tid == 0) {
            float e1 = -INFINITY, e2v = -INFINITY; int i1 = 0, i2 = 0;
            #pragma unroll
            for (int j = 0; j < EPG; ++j) {
                float v = el_s[j];
                if (v > e1)       { e2v = e1; i2 = i1; e1 = v; i1 = j; }
                else if (v > e2v) { e2v = v; i2 = j; }
            }
            float es = 0.f;
            #pragma unroll
            for (int j = 0; j < EPG; ++j) {
                float e = expf(el_s[j] - e1);
                rp_row[j] = e;
                es += e;
            }
            float inv = 1.f / es;
            float gp = s_gp;
            #pragma unroll
            for (int j = 0; j < EPG; ++j) rp_row[j] *= inv * gp;
            float v1 = expf(el_s[i1] - e1) * inv;
            float v2 = expf(el_s[i2] - e1) * inv;
            float u2 = s_u2;
            float denom = v1 + v2 * u2;
            s_n1 = v1 / denom; s_n2 = v2 * u2 / denom;
            s_e1 = gi * EPG + i1; s_e2 = gi * EPG + i2;
        }
        __syncthreads();

        if (tid < NE) {
            const int e = tid;
            float u2 = s_u2;
            float newD = (e == s_e1 ? 1.f : 0.f) + (e == s_e2 ? u2 : 0.f);
            float newC = (e == s_e1 ? s_n1 : 0.f) + (e == s_e2 ? s_n2 : 0.f);
            float newR = ((e >> 4) == gi) ? rp_row[e & 15] : 0.f;
            size_t ob = (size_t)tok * NE + e;
            float oldD = out[ob];
            float oldR = out[(size_t)2 * T_TOKENS * NE + ob];
            out[ob] = newD;
            out[(size_t)T_TOKENS * NE + ob] = newC;
            out[(size_t)2 * T_TOKENS * NE + ob] = newR;
            float dD = newD - oldD, dR = newR - oldR;
            if (dD != 0.f) atomicAdd(&sums[e], dD);
            if (dR != 0.f) atomicAdd(&sums[NE + e], dR);
        }
        __syncthreads();
    }
}

__global__ void moe_finalize(const float* __restrict__ sums, float* __restrict__ out) {
    int l = threadIdx.x;
    float v = sums[l] * sums[NE + l];
    #pragma unroll
    for (int off = 32; off; off >>= 1) v += __shfl_down(v, off, 64);
    if (l == 0) {
        float N = (float)T_TOKENS;
        out[(size_t)3 * T_TOKENS * NE] = v * (float)NE / (N * N);
    }
}

extern "C" void kernel_launch(void* const* d_in, const int* in_sizes, int n_in,
                              void* d_out, int out_size, void* d_ws, size_t ws_size,
                              hipStream_t stream) {
    const float* x  = (const float*)d_in[0];
    const float* Wg = (const float*)d_in[1];
    const float* We = (const float*)d_in[2];
    const float* W1 = (const float*)d_in[3];
    const float* b1 = (const float*)d_in[4];
    const float* W2 = (const float*)d_in[5];
    const float* b2 = (const float*)d_in[6];
    const int* minE = (const int*)d_in[7];
    const int* maxE = (const int*)d_in[8];
    float* out = (float*)d_out;
    float* ws  = (float*)d_ws;

    float* wfrag = ws;
    float* part  = ws + P_OFF;
    float* sums  = ws + SUM_OFF;
    int*   cnt   = (int*)(ws + CNT_OFF);
    int4*  list  = (int4*)(ws + LIST_OFF);

    moe_prep<<<64 * NT, 64, 0, stream>>>(Wg, We, W1, wfrag, sums, cnt);
    moe_gemm<<<64 * KS, 512, 0, stream>>>(x, wfrag, part);
    moe_epi<<<T_TOKENS / 16, 256, 0, stream>>>(part, b1, W2, b2, minE, maxE,
                                               out, sums, cnt, list);
    moe_fix<<<2048, 256, 0, stream>>>(x, Wg, We, W1, b1, W2, b2, minE, maxE,
                                      out, sums, cnt, list);
    moe_finalize<<<1, 64, 0, stream>>>(sums, out);
}

// Round 14
// 79.586 us; speedup vs baseline: 1.8595x; 1.5779x over previous
//
#include <hip/hip_runtime.h>
#include <cmath>

#define T_TOKENS 16384
#define DIM 2048
#define NG 4
#define EPG 16
#define NE 64
#define NJ2 68          // 4 group + 64 expert rows (complexity MLP is dead: k==1 always)
#define NT2 5           // n-tiles of 16 (80 padded)
#define BM 64           // tokens per block
#define BK 64           // k per iteration (2 ksteps of 32)
#define NITER (DIM / BK)    // 32
#define TAU 0.02f

#define XBUF_B 16384    // 64 tok * 256 B
#define WBUF_B 10240    // 10 cells * 1 KB

typedef __attribute__((ext_vector_type(8))) short bf16x8;
typedef __attribute__((ext_vector_type(4))) float f32x4;

// ws float-offsets
#define WF_FLOATS (64 * NT2 * 64 * 4)   // 81920 floats (fragment-linear bf16 weights)
#define SUM_OFF WF_FLOATS               // 128 floats: usage, rp
#define CNT_OFF (SUM_OFF + 128)
#define LIST_OFF (CNT_OFF + 4)          // int4 entries

static __device__ inline unsigned bf16rne(float x) {
    unsigned u = __float_as_uint(x);
    return (u + 0x7FFFu + ((u >> 16) & 1u)) >> 16;
}

#define GLOAD_LDS(gsrc, ldst) \
    __builtin_amdgcn_global_load_lds( \
        (const __attribute__((address_space(1))) void*)(gsrc), \
        (__attribute__((address_space(3))) void*)(ldst), 16, 0, 0)

// Fragment-linear bf16 weights: [kstep 64][tile 5][lane 64][16B].
// Row j: j<4 -> Wg[j]; 4<=j<68 -> We[j-4]; else 0.
__global__ void moe_prep(const float* __restrict__ Wg, const float* __restrict__ We,
                         float* __restrict__ ws, float* __restrict__ sums,
                         int* __restrict__ cnt) {
    int bid = blockIdx.x;                 // 320
    int kstep = bid / NT2, nt = bid % NT2;
    int lane = threadIdx.x;               // 64
    if (bid == 0) {
        sums[lane] = 0.f; sums[64 + lane] = 0.f;
        if (lane == 0) *cnt = 0;
    }
    int row = nt * 16 + (lane & 15);
    int k0 = kstep * 32 + (lane >> 4) * 8;
    const float* src = nullptr;
    if (row < NG)            src = Wg + (size_t)row * DIM;
    else if (row < NJ2)      src = We + (size_t)(row - NG) * DIM;
    unsigned r0 = 0, r1 = 0, r2 = 0, r3 = 0;
    if (src) {
        r0 = bf16rne(src[k0 + 0]) | (bf16rne(src[k0 + 1]) << 16);
        r1 = bf16rne(src[k0 + 2]) | (bf16rne(src[k0 + 3]) << 16);
        r2 = bf16rne(src[k0 + 4]) | (bf16rne(src[k0 + 5]) << 16);
        r3 = bf16rne(src[k0 + 6]) | (bf16rne(src[k0 + 7]) << 16);
    }
    ((uint4*)ws)[(size_t)(kstep * NT2 + nt) * 64 + lane] = make_uint4(r0, r1, r2, r3);
}

// Fused GEMM + epilogue: 256 blocks x 512 threads (8 waves), 64 tokens/block.
// Wave = (mt = wave&3) x (nh = wave>>2): nh0 tiles {0,1,2}, nh1 tiles {3,4}.
__global__ __launch_bounds__(512, 2) void moe_fused(
    const float* __restrict__ x, const float* __restrict__ wfrag,
    float* __restrict__ out, float* __restrict__ sums,
    int* __restrict__ cnt, int4* __restrict__ list) {
    __shared__ __align__(16) char smem[2 * XBUF_B + 2 * WBUF_B];  // 52 KB; slog overlays
    __shared__ float rp_s[BM * 17];
    __shared__ int   sc_e1[BM];
    __shared__ float s_usage[NE], s_rp[NE];

    const int tid = threadIdx.x;
    const int wave = tid >> 6, lane = tid & 63;
    const int l15 = lane & 15, lq = lane >> 4;
    const int T0 = blockIdx.x * BM;

    if (tid < NE) { s_usage[tid] = 0.f; s_rp[tid] = 0.f; }

    const uint4* wg = (const uint4*)wfrag;
    const int mt = wave & 3, nh = wave >> 2;
    const int ctok = mt * 16 + l15;
    const int csw = ctok & 7;

    f32x4 acc0 = (f32x4){0.f,0.f,0.f,0.f};
    f32x4 acc1 = (f32x4){0.f,0.f,0.f,0.f};
    f32x4 acc2 = (f32x4){0.f,0.f,0.f,0.f};

    auto stage = [&](int it) {
        char* xb = smem + (it & 1) * XBUF_B;
        char* wb = smem + 2 * XBUF_B + (it & 1) * WBUF_B;
        const int kf = it * BK;
        #pragma unroll
        for (int j = 0; j < 2; ++j) {
            const int tok = wave * 8 + j * 4 + (lane >> 4);
            const float* src = x + (size_t)(T0 + tok) * DIM + kf
                             + (((lane & 15) ^ (tok & 7)) << 2);
            GLOAD_LDS(src, xb + (wave * 8 + j * 4) * 256);
        }
        if (wave < NT2) {
            #pragma unroll
            for (int ks = 0; ks < 2; ++ks) {
                const int kstep = it * 2 + ks;
                GLOAD_LDS(wg + ((size_t)kstep * NT2 + wave) * 64 + lane,
                          wb + (ks * NT2 + wave) * 1024);
            }
        }
    };

    stage(0);
    #pragma unroll 1
    for (int it = 0; it < NITER; ++it) {
        __syncthreads();                       // stage(it) landed; prev buf free
        if (it + 1 < NITER) stage(it + 1);
        const char* xb = smem + (it & 1) * XBUF_B;
        const char* wb = smem + 2 * XBUF_B + (it & 1) * WBUF_B;
        #pragma unroll
        for (int ks = 0; ks < 2; ++ks) {
            const int u0 = ks * 8 + lq * 2;
            uint4 lo = *(const uint4*)(xb + ctok * 256 + ((u0 ^ csw) << 4));
            uint4 hi = *(const uint4*)(xb + ctok * 256 + (((u0 + 1) ^ csw) << 4));
            union { unsigned u[4]; bf16x8 v; } af;
            af.u[0] = (lo.x >> 16) | (lo.y & 0xFFFF0000u);
            af.u[1] = (lo.z >> 16) | (lo.w & 0xFFFF0000u);
            af.u[2] = (hi.x >> 16) | (hi.y & 0xFFFF0000u);
            af.u[3] = (hi.z >> 16) | (hi.w & 0xFFFF0000u);
            if (nh == 0) {
                bf16x8 b0 = *(const bf16x8*)(wb + (ks * NT2 + 0) * 1024 + lane * 16);
                bf16x8 b1 = *(const bf16x8*)(wb + (ks * NT2 + 1) * 1024 + lane * 16);
                bf16x8 b2 = *(const bf16x8*)(wb + (ks * NT2 + 2) * 1024 + lane * 16);
                acc0 = __builtin_amdgcn_mfma_f32_16x16x32_bf16(af.v, b0, acc0, 0, 0, 0);
                acc1 = __builtin_amdgcn_mfma_f32_16x16x32_bf16(af.v, b1, acc1, 0, 0, 0);
                acc2 = __builtin_amdgcn_mfma_f32_16x16x32_bf16(af.v, b2, acc2, 0, 0, 0);
            } else {
                bf16x8 b0 = *(const bf16x8*)(wb + (ks * NT2 + 3) * 1024 + lane * 16);
                bf16x8 b1 = *(const bf16x8*)(wb + (ks * NT2 + 4) * 1024 + lane * 16);
                acc0 = __builtin_amdgcn_mfma_f32_16x16x32_bf16(af.v, b0, acc0, 0, 0, 0);
                acc1 = __builtin_amdgcn_mfma_f32_16x16x32_bf16(af.v, b1, acc1, 0, 0, 0);
            }
        }
    }
    __syncthreads();   // all buffer reads done -> overlay slog

    float* slog = (float*)smem;            // [64][81] = 20.7 KB
    #pragma unroll
    for (int r = 0; r < 4; ++r) {
        const int row = mt * 16 + lq * 4 + r;
        if (nh == 0) {
            slog[row * 81 + 0 * 16 + l15] = acc0[r];
            slog[row * 81 + 1 * 16 + l15] = acc1[r];
            slog[row * 81 + 2 * 16 + l15] = acc2[r];
        } else {
            slog[row * 81 + 3 * 16 + l15] = acc0[r];
            slog[row * 81 + 4 * 16 + l15] = acc1[r];
        }
    }
    __syncthreads();

    // epilogue: 16-lane group per token, 2 halves of 32 tokens
    #pragma unroll
    for (int half = 0; half < 2; ++half) {
        const int t = (tid >> 4) + half * 32;
        const int q = tid & 15;
        const int tok = T0 + t;
        const float* o = slog + t * 81;

        float gl0 = o[0], gl1 = o[1], gl2 = o[2], gl3 = o[3];
        float gm = gl0; int gi = 0;
        if (gl1 > gm) { gm = gl1; gi = 1; }
        if (gl2 > gm) { gm = gl2; gi = 2; }
        if (gl3 > gm) { gm = gl3; gi = 3; }
        float g2 = -INFINITY;
        if (gi != 0 && gl0 > g2) g2 = gl0;
        if (gi != 1 && gl1 > g2) g2 = gl1;
        if (gi != 2 && gl2 > g2) g2 = gl2;
        if (gi != 3 && gl3 > g2) g2 = gl3;
        bool flagG = (gm - g2) < TAU;
        float gsum = expf(gl0 - gm) + expf(gl1 - gm) + expf(gl2 - gm) + expf(gl3 - gm);
        float gp = 1.f / gsum;

        float el = o[NG + gi * EPG + q];
        float v1v = el; int i1 = q;
        #pragma unroll
        for (int off = 8; off; off >>= 1) {
            float ov = __shfl_xor(v1v, off, 16);
            int   oi = __shfl_xor(i1, off, 16);
            if (ov > v1v || (ov == v1v && oi < i1)) { v1v = ov; i1 = oi; }
        }
        float v2v = (q == i1) ? -INFINITY : el;
        #pragma unroll
        for (int off = 8; off; off >>= 1)
            v2v = fmaxf(v2v, __shfl_xor(v2v, off, 16));
        bool flagE = (v1v - v2v) < TAU;

        float ep = expf(el - v1v);
        float es = ep;
        #pragma unroll
        for (int off = 8; off; off >>= 1) es += __shfl_xor(es, off, 16);
        float inv = 1.f / es;
        rp_s[t * 17 + q] = gp * ep * inv;

        if (q == 0) {
            sc_e1[t] = gi * EPG + i1;
            if (flagG || flagE) {
                int p = atomicAdd(cnt, 1);
                list[p] = make_int4(tok, 0, 0, 0);
            }
        }
    }
    __syncthreads();

    float* outD = out;
    float* outC = out + (size_t)T_TOKENS * NE;
    float* outR = out + (size_t)2 * T_TOKENS * NE;
    for (int idx = tid; idx < BM * NE; idx += 512) {
        int t = idx >> 6, e = idx & 63;
        int e1i = sc_e1[t];
        int gi = e1i >> 4;
        float disp = (e == e1i) ? 1.f : 0.f;           // k==1: dispatch == combine == one-hot
        float rpv  = ((e >> 4) == gi) ? rp_s[t * 17 + (e & 15)] : 0.f;
        size_t ob = (size_t)(T0 + t) * NE + e;
        outD[ob] = disp; outC[ob] = disp; outR[ob] = rpv;
        atomicAdd(&s_usage[e], disp);
        atomicAdd(&s_rp[e], rpv);
    }
    __syncthreads();
    if (tid < NE) {
        atomicAdd(&sums[tid], s_usage[tid]);
        atomicAdd(&sums[NE + tid], s_rp[tid]);
    }
}

// exact fixup: one block (4 waves) per flagged token; group + chosen-group experts only
__global__ __launch_bounds__(256, 4) void moe_fix(
    const float* __restrict__ x, const float* __restrict__ Wg,
    const float* __restrict__ We, float* __restrict__ out,
    float* __restrict__ sums, const int* __restrict__ cnt,
    const int4* __restrict__ list) {
    __shared__ float gl_s[NG];
    __shared__ float el_s[EPG];
    __shared__ float rp_row[EPG];
    __shared__ int   s_gi, s_e1;
    __shared__ float s_gp;

    const int tid = threadIdx.x;
    const int wave = tid >> 6, lane = tid & 63;
    const int n = *cnt;

    for (int i = blockIdx.x; i < n; i += gridDim.x) {
        const int tok = list[i].x;
        const float* xrow = x + (size_t)tok * DIM;
        float xr[32];
        #pragma unroll
        for (int m = 0; m < 32; ++m) xr[m] = xrow[lane + m * 64];

        auto dotf = [&](const float* w) -> float {
            float s = 0.f;
            #pragma unroll
            for (int m = 0; m < 32; ++m) s = fmaf(xr[m], w[lane + m * 64], s);
            #pragma unroll
            for (int off = 32; off; off >>= 1) s += __shfl_xor(s, off, 64);
            return s;
        };

        {
            float g = dotf(Wg + (size_t)wave * DIM);
            if (lane == 0) gl_s[wave] = g;
        }
        __syncthreads();

        if (tid == 0) {
            float gm = -INFINITY; int gi = 0;
            #pragma unroll
            for (int g = 0; g < NG; ++g)
                if (gl_s[g] > gm) { gm = gl_s[g]; gi = g; }
            float gsum = 0.f;
            #pragma unroll
            for (int g = 0; g < NG; ++g) gsum += expf(gl_s[g] - gm);
            s_gp = 1.f / gsum;
            s_gi = gi;
        }
        __syncthreads();

        const int gi = s_gi;
        for (int j = wave; j < EPG; j += 4) {
            float e = dotf(We + (size_t)(gi * EPG + j) * DIM);
            if (lane == 0) el_s[j] = e;
        }
        __syncthreads();

        if (tid == 0) {
            float e1 = -INFINITY; int i1 = 0;
            #pragma unroll
            for (int j = 0; j < EPG; ++j)
                if (el_s[j] > e1) { e1 = el_s[j]; i1 = j; }
            float es = 0.f;
            #pragma unroll
            for (int j = 0; j < EPG; ++j) {
                float e = expf(el_s[j] - e1);
                rp_row[j] = e;
                es += e;
            }
            float sc = s_gp / es;
            #pragma unroll
            for (int j = 0; j < EPG; ++j) rp_row[j] *= sc;
            s_e1 = gi * EPG + i1;
        }
        __syncthreads();

        if (tid < NE) {
            const int e = tid;
            float newD = (e == s_e1) ? 1.f : 0.f;
            float newR = ((e >> 4) == gi) ? rp_row[e & 15] : 0.f;
            size_t ob = (size_t)tok * NE + e;
            float oldD = out[ob];
            float oldR = out[(size_t)2 * T_TOKENS * NE + ob];
            out[ob] = newD;
            out[(size_t)T_TOKENS * NE + ob] = newD;
            out[(size_t)2 * T_TOKENS * NE + ob] = newR;
            float dD = newD - oldD, dR = newR - oldR;
            if (dD != 0.f) atomicAdd(&sums[e], dD);
            if (dR != 0.f) atomicAdd(&sums[NE + e], dR);
        }
        __syncthreads();
    }
}

__global__ void moe_finalize(const float* __restrict__ sums, float* __restrict__ out) {
    int l = threadIdx.x;
    float v = sums[l] * sums[NE + l];
    #pragma unroll
    for (int off = 32; off; off >>= 1) v += __shfl_down(v, off, 64);
    if (l == 0) {
        float N = (float)T_TOKENS;
        out[(size_t)3 * T_TOKENS * NE] = v * (float)NE / (N * N);
    }
}

extern "C" void kernel_launch(void* const* d_in, const int* in_sizes, int n_in,
                              void* d_out, int out_size, void* d_ws, size_t ws_size,
                              hipStream_t stream) {
    const float* x  = (const float*)d_in[0];
    const float* Wg = (const float*)d_in[1];
    const float* We = (const float*)d_in[2];
    float* out = (float*)d_out;
    float* ws  = (float*)d_ws;

    float* wfrag = ws;
    float* sums  = ws + SUM_OFF;
    int*   cnt   = (int*)(ws + CNT_OFF);
    int4*  list  = (int4*)(ws + LIST_OFF);

    moe_prep<<<64 * NT2, 64, 0, stream>>>(Wg, We, wfrag, sums, cnt);
    moe_fused<<<T_TOKENS / BM, 512, 0, stream>>>(x, wfrag, out, sums, cnt, list);
    moe_fix<<<1024, 256, 0, stream>>>(x, Wg, We, out, sums, cnt, list);
    moe_finalize<<<1, 64, 0, stream>>>(sums, out);
}